// Round 19
// baseline (246.853 us; speedup 1.0000x reference)
//
#include <hip/hip_runtime.h>
#include <hip/hip_bf16.h>
#include <math.h>

typedef __bf16 bf16;
typedef __attribute__((ext_vector_type(8))) __bf16 bf16x8;
typedef __attribute__((ext_vector_type(4))) __bf16 bf16x4;
typedef __attribute__((ext_vector_type(4))) float f32x4;
typedef __attribute__((ext_vector_type(16))) float f32x16;

#define EXP2N __builtin_amdgcn_exp2f   // bare v_exp_f32 (1 VALU op)

static __device__ __forceinline__ void gload_lds16(const bf16* g, bf16* l) {
  __builtin_amdgcn_global_load_lds((const __attribute__((address_space(1))) void*)g,
                                   (__attribute__((address_space(3))) void*)l, 16, 0, 0);
}

// ---------------------------------------------------------------- LayerNorm
__global__ __launch_bounds__(256) void ln_kernel(
    const float* __restrict__ x, const float* __restrict__ gam, const float* __restrict__ bet,
    bf16* __restrict__ nxo)
{
  const int token = blockIdx.x;
  const int t = threadIdx.x, w = t >> 6, l = t & 63;
  __shared__ float red1[4], red2[4];
  float4 xv = ((const float4*)(x + (size_t)token * 1024))[t];
  float s  = xv.x + xv.y + xv.z + xv.w;
  float sq = xv.x*xv.x + xv.y*xv.y + xv.z*xv.z + xv.w*xv.w;
  #pragma unroll
  for (int off = 32; off > 0; off >>= 1) { s += __shfl_xor(s, off); sq += __shfl_xor(sq, off); }
  if (l == 0) { red1[w] = s; red2[w] = sq; }
  __syncthreads();
  s  = red1[0] + red1[1] + red1[2] + red1[3];
  sq = red2[0] + red2[1] + red2[2] + red2[3];
  const float mu  = s * (1.f / 1024.f);
  const float var = sq * (1.f / 1024.f) - mu * mu;
  const float rs  = rsqrtf(var + 1e-5f);
  float4 gv = ((const float4*)gam)[t];
  float4 bv = ((const float4*)bet)[t];
  bf16x4 pk = {(bf16)((xv.x - mu) * rs * gv.x + bv.x),
               (bf16)((xv.y - mu) * rs * gv.y + bv.y),
               (bf16)((xv.z - mu) * rs * gv.z + bv.z),
               (bf16)((xv.w - mu) * rs * gv.w + bv.w)};
  *(bf16x4*)(nxo + (size_t)token * 1024 + t * 4) = pk;
}

// --------------------------------------------------- route pool (from logits)
__global__ __launch_bounds__(256) void route_pool_kernel(
    const float* __restrict__ logits, const float* __restrict__ imp,
    float* __restrict__ racc, int ng, int gbase)
{
  const int w = threadIdx.x >> 6, l = threadIdx.x & 63;
  const int token = blockIdx.x * 4 + w;
  const int b = token >> 11;
  const int g = l >> 4, e = l & 15;
  if (g < ng) {
    float v = logits[(size_t)token * 128 + g * 16 + e];
    float mx = v;
    #pragma unroll
    for (int off = 1; off < 16; off <<= 1) mx = fmaxf(mx, __shfl_xor(mx, off));
    float ex = __expf(v - mx);
    float sm = ex;
    #pragma unroll
    for (int off = 1; off < 16; off <<= 1) sm += __shfl_xor(sm, off);
    atomicAdd(racc + ((((size_t)(token & 31)) * 5 + gbase + g) * 2 + b) * 16 + e,
              imp[token] * (ex / sm));
  }
}

// ----------------------------------- fused phase-A mixes (sct + eqt/ekt/evt)
__global__ __launch_bounds__(256) void mixA_kernel(
    const float* __restrict__ comp, const float* __restrict__ expd,
    const float* __restrict__ racc, bf16* __restrict__ sct, bf16* __restrict__ eqt)
{
  const int xb = blockIdx.x, sel = blockIdx.y, b = blockIdx.z;
  const int t = threadIdx.x;
  __shared__ float tile[64][65];
  __shared__ float psh[3][16];
  __shared__ float dsh[3];
  if (sel == 0) {
    if (t < 16) {
      float s = 0.f;
      for (int sl = 0; sl < 32; ++sl) s += racc[(((size_t)sl * 5 + 0) * 2 + b) * 16 + t];
      psh[0][t] = s;
    }
  } else {
    if (t < 48) {
      const int g = t >> 4, e = t & 15;
      float s = 0.f;
      for (int sl = 0; sl < 32; ++sl) s += racc[(((size_t)sl * 5 + 1 + g) * 2 + b) * 16 + e];
      psh[g][e] = s;
    }
  }
  __syncthreads();
  if (t < ((sel == 0) ? 1 : 3)) {
    float den = 1e-8f;
    #pragma unroll
    for (int e = 0; e < 16; ++e) den += psh[t][e];
    dsh[t] = 1.0f / den;
  }
  __syncthreads();

  const int ri = t >> 2, cc = (t & 3) << 4;
  if (sel == 0) {
    const int i0 = (xb & 15) * 64, j0 = (xb >> 4) * 64;
    const float inv = dsh[0];
    float acc[16];
    #pragma unroll
    for (int k = 0; k < 16; ++k) acc[k] = 0.f;
    const float* src0 = comp + ((size_t)(i0 + ri)) * 256 + j0 + cc;
    #pragma unroll 4
    for (int n = 0; n < 16; ++n) {
      const float wv = psh[0][n] * inv;
      const float4* sp = (const float4*)(src0 + (size_t)n * 262144);
      #pragma unroll
      for (int q = 0; q < 4; ++q) {
        float4 v = sp[q];
        acc[q*4+0] += wv * v.x; acc[q*4+1] += wv * v.y;
        acc[q*4+2] += wv * v.z; acc[q*4+3] += wv * v.w;
      }
    }
    #pragma unroll
    for (int k = 0; k < 16; ++k) tile[ri][cc + k] = acc[k];
    __syncthreads();
    union { bf16 h[16]; bf16x8 v[2]; } ob;
    #pragma unroll
    for (int k = 0; k < 16; ++k) ob.h[k] = (bf16)tile[cc + k][ri];
    bf16* dst = sct + ((size_t)b * 256 + j0 + ri) * 1024 + i0 + cc;
    ((bf16x8*)dst)[0] = ob.v[0];
    ((bf16x8*)dst)[1] = ob.v[1];
  } else {
    const int i0 = (xb & 3) * 64, j0 = (xb >> 2) * 64;
    const float inv0 = dsh[0], inv1 = dsh[1], inv2 = dsh[2];
    float acc[3][16];
    #pragma unroll
    for (int g = 0; g < 3; ++g)
      #pragma unroll
      for (int k = 0; k < 16; ++k) acc[g][k] = 0.f;
    const float* src0 = expd + ((size_t)(i0 + ri)) * 1024 + j0 + cc;
    #pragma unroll 2
    for (int n = 0; n < 16; ++n) {
      const float w0 = psh[0][n] * inv0;
      const float w1 = psh[1][n] * inv1;
      const float w2 = psh[2][n] * inv2;
      const float4* sp = (const float4*)(src0 + (size_t)n * 262144);
      #pragma unroll
      for (int q = 0; q < 4; ++q) {
        float4 v = sp[q];
        acc[0][q*4+0] += w0 * v.x; acc[0][q*4+1] += w0 * v.y;
        acc[0][q*4+2] += w0 * v.z; acc[0][q*4+3] += w0 * v.w;
        acc[1][q*4+0] += w1 * v.x; acc[1][q*4+1] += w1 * v.y;
        acc[1][q*4+2] += w1 * v.z; acc[1][q*4+3] += w1 * v.w;
        acc[2][q*4+0] += w2 * v.x; acc[2][q*4+1] += w2 * v.y;
        acc[2][q*4+2] += w2 * v.z; acc[2][q*4+3] += w2 * v.w;
      }
    }
    #pragma unroll 1
    for (int g = 0; g < 3; ++g) {
      __syncthreads();
      #pragma unroll
      for (int k = 0; k < 16; ++k) tile[ri][cc + k] = acc[g][k];
      __syncthreads();
      union { bf16 h[16]; bf16x8 v[2]; } ob;
      #pragma unroll
      for (int k = 0; k < 16; ++k) ob.h[k] = (bf16)tile[cc + k][ri];
      bf16* dst = eqt + (size_t)g * 524288 + ((size_t)b * 1024 + j0 + ri) * 256 + i0 + cc;
      ((bf16x8*)dst)[0] = ob.v[0];
      ((bf16x8*)dst)[1] = ob.v[1];
    }
  }
}

// ------------------------------------- phase-B mix (mct, group 4, inline rw)
__global__ __launch_bounds__(256) void mixB_kernel(
    const float* __restrict__ comp, const float* __restrict__ racc,
    bf16* __restrict__ out)
{
  const int xb = blockIdx.x, b = blockIdx.z;
  const int t = threadIdx.x;
  __shared__ float tile[64][65];
  __shared__ float psh[16];
  __shared__ float dsh1;
  if (t < 16) {
    float s = 0.f;
    for (int sl = 0; sl < 32; ++sl) s += racc[(((size_t)sl * 5 + 4) * 2 + b) * 16 + t];
    psh[t] = s;
  }
  __syncthreads();
  if (t == 0) {
    float den = 1e-8f;
    #pragma unroll
    for (int e = 0; e < 16; ++e) den += psh[e];
    dsh1 = 1.0f / den;
  }
  __syncthreads();
  const int ri = t >> 2, cc = (t & 3) << 4;
  const int i0 = (xb & 15) * 64, j0 = (xb >> 4) * 64;
  const float inv = dsh1;
  float acc[16];
  #pragma unroll
  for (int k = 0; k < 16; ++k) acc[k] = 0.f;
  const float* src0 = comp + ((size_t)(i0 + ri)) * 256 + j0 + cc;
  #pragma unroll 4
  for (int n = 0; n < 16; ++n) {
    const float wv = psh[n] * inv;
    const float4* sp = (const float4*)(src0 + (size_t)n * 262144);
    #pragma unroll
    for (int q = 0; q < 4; ++q) {
      float4 v = sp[q];
      acc[q*4+0] += wv * v.x; acc[q*4+1] += wv * v.y;
      acc[q*4+2] += wv * v.z; acc[q*4+3] += wv * v.w;
    }
  }
  #pragma unroll
  for (int k = 0; k < 16; ++k) tile[ri][cc + k] = acc[k];
  __syncthreads();
  union { bf16 h[16]; bf16x8 v[2]; } ob;
  #pragma unroll
  for (int k = 0; k < 16; ++k) ob.h[k] = (bf16)tile[cc + k][ri];
  bf16* dst = out + ((size_t)b * 256 + j0 + ri) * 1024 + i0 + cc;
  ((bf16x8*)dst)[0] = ob.v[0];
  ((bf16x8*)dst)[1] = ob.v[1];
}

// ------------------------------------------------------------ f32 -> bf16
__global__ void cvt_bf16_kernel(const float* __restrict__ in, bf16* __restrict__ out, int n4)
{
  const int i = blockIdx.x * 256 + threadIdx.x;
  if (i < n4) {
    float4 v = ((const float4*)in)[i];
    bf16x4 o = {(bf16)v.x, (bf16)v.y, (bf16)v.z, (bf16)v.w};
    ((bf16x4*)out)[i] = o;
  }
}

// -------------------- all weight conversions: Wcat(pad) + WO + kK in one
__global__ void cvt_all_kernel(
    const float* __restrict__ w0, const float* __restrict__ w1,
    const float* __restrict__ w2, const float* __restrict__ w3,
    const float* __restrict__ w4, bf16* __restrict__ wcat,
    const float* __restrict__ wo, bf16* __restrict__ woo,
    const float* __restrict__ kk, bf16* __restrict__ kko)
{
  int i = blockIdx.x * 256 + threadIdx.x;
  if (i < 32768) {
    const int seg = i >> 12;
    bf16x4 o;
    if (seg < 5) {
      const float* src = (seg == 0) ? w0 : (seg == 1) ? w1 : (seg == 2) ? w2
                       : (seg == 3) ? w3 : w4;
      float4 v = ((const float4*)src)[i & 4095];
      o = (bf16x4){(bf16)v.x, (bf16)v.y, (bf16)v.z, (bf16)v.w};
    } else {
      o = (bf16x4){(bf16)0.f, (bf16)0.f, (bf16)0.f, (bf16)0.f};
    }
    ((bf16x4*)wcat)[i] = o;
  } else {
    i -= 32768;
    if (i < 262144) {
      float4 v = ((const float4*)wo)[i];
      ((bf16x4*)woo)[i] = (bf16x4){(bf16)v.x, (bf16)v.y, (bf16)v.z, (bf16)v.w};
    } else {
      i -= 262144;
      float4 v = ((const float4*)kk)[i];
      ((bf16x4*)kko)[i] = (bf16x4){(bf16)v.x, (bf16)v.y, (bf16)v.z, (bf16)v.w};
    }
  }
}

// --------------------------------------------------------------- GEMM (Bt)
// 8-wave blocks, global_load_lds staging, and a 4-buffer deep-prefetch
// pipeline: loads issue TWO K-tiles ahead, s_waitcnt vmcnt(4) waits only
// for the current tile's 2 loads, ONE raw s_barrier per K-step. Loads get
// ~2 iterations (~400-700 cy) to land vs <100 cy with the drain-barrier
// structure -- removes the per-step latency stall in this latency-bound
// regime. Hazard audit: iter k writes buf[(k+2)&3] = buf[(k-2)&3], last
// read in compute(k-2), which all waves complete before barrier(k-1).
// CMODE: 0 = bf16 out, 1 = f32 out, 2 = f32 out + f32 resid,
//        3 = bf16 out head-major, 4/5 = f32 atomicAdd split-K variants,
//        6 = dual bf16 out (Q normal + K head-major*scale).
template<int CMODE>
__global__ __launch_bounds__(512) void gemm_bt(
    const bf16* __restrict__ A, const bf16* __restrict__ Bt, void* __restrict__ Cp,
    const float* __restrict__ resid, int M, int N, int K, int lda, int ldb,
    long sA, long sB, long sC, float scale)
{
  __shared__ alignas(16) bf16 As[4][4096];
  __shared__ alignas(16) bf16 Bs[4][4096];
  const int t = threadIdx.x, w = t >> 6, l = t & 63;
  const int llo = l & 15, lhi = l >> 4;
  const int wm = w >> 2, wn = w & 3;
  const int m0 = blockIdx.y * 128, n0 = blockIdx.x * 128;
  const int z = blockIdx.z;
  const bf16* Ab;
  const bf16* Bb;
  if (CMODE == 5) {
    Ab = A  + (size_t)(z >> 1) * sA + (size_t)(z & 1) * K;
    Bb = Bt + (size_t)(z >> 1) * sB + (size_t)(z & 1) * K;
  } else if (CMODE == 6) {
    Ab = A  + (size_t)(z & 1) * sA;
    Bb = Bt + (size_t)(z >> 1) * 524288 + (size_t)(z & 1) * sB;
  } else {
    Ab = A  + (size_t)z * sA;
    Bb = Bt + (size_t)z * sB;
  }
  f32x4 acc[4][2];
  #pragma unroll
  for (int i = 0; i < 4; ++i)
    #pragma unroll
    for (int j = 0; j < 2; ++j) acc[i][j] = (f32x4){0.f, 0.f, 0.f, 0.f};

  const int arow = t >> 2, akb = t & 3;
  const int akbs = akb ^ ((arow >> 1) & 3);      // pre-swizzled source column
  const bf16* asrc = Ab + (size_t)(m0 + arow) * lda + akbs * 8;
  const bf16* bsrc = Bb + (size_t)(n0 + arow) * ldb + akbs * 8;

  gload_lds16(asrc,      &As[0][t * 8]);
  gload_lds16(bsrc,      &Bs[0][t * 8]);
  gload_lds16(asrc + 32, &As[1][t * 8]);
  gload_lds16(bsrc + 32, &Bs[1][t * 8]);

  const int nt = K >> 5;
  for (int it = 0; it < nt; ++it) {
    const int kt = it << 5;
    if (it + 2 < nt) {
      const int nb = (it + 2) & 3;
      gload_lds16(asrc + kt + 64, &As[nb][t * 8]);
      gload_lds16(bsrc + kt + 64, &Bs[nb][t * 8]);
      asm volatile("s_waitcnt vmcnt(4)" ::: "memory");
    } else if (it + 1 < nt) {
      asm volatile("s_waitcnt vmcnt(2)" ::: "memory");
    } else {
      asm volatile("s_waitcnt vmcnt(0)" ::: "memory");
    }
    __builtin_amdgcn_s_barrier();
    const bf16* Asb = As[it & 3];
    const bf16* Bsb = Bs[it & 3];
    bf16x8 af[4], bfr[2];
    #pragma unroll
    for (int fi = 0; fi < 4; ++fi) {
      int r = wm * 64 + fi * 16 + llo;
      af[fi] = *(const bf16x8*)((const char*)Asb + (r * 64 + ((lhi * 16) ^ (((r >> 1) & 3) << 4))));
    }
    #pragma unroll
    for (int fj = 0; fj < 2; ++fj) {
      int c = wn * 32 + fj * 16 + llo;
      bfr[fj] = *(const bf16x8*)((const char*)Bsb + (c * 64 + ((lhi * 16) ^ (((c >> 1) & 3) << 4))));
    }
    #pragma unroll
    for (int fi = 0; fi < 4; ++fi)
      #pragma unroll
      for (int fj = 0; fj < 2; ++fj)
        acc[fi][fj] = __builtin_amdgcn_mfma_f32_16x16x32_bf16(af[fi], bfr[fj], acc[fi][fj], 0, 0, 0);
  }

  size_t cbase;
  if (CMODE == 4) cbase = 0;
  else if (CMODE == 5) cbase = (size_t)(z >> 1) * sC;
  else if (CMODE == 6) cbase = (size_t)(z & 1) * sC;
  else cbase = (size_t)z * sC;

  #pragma unroll
  for (int fi = 0; fi < 4; ++fi)
    #pragma unroll
    for (int fj = 0; fj < 2; ++fj)
      #pragma unroll
      for (int jj = 0; jj < 4; ++jj) {
        int r = m0 + wm * 64 + fi * 16 + lhi * 4 + jj;
        int c = n0 + wn * 32 + fj * 16 + llo;
        size_t idx = cbase + (size_t)r * N + c;
        float v = acc[fi][fj][jj] * ((CMODE == 6) ? 1.0f : scale);
        if (CMODE == 0) {
          ((bf16*)Cp)[idx] = (bf16)v;
        } else if (CMODE == 3) {
          size_t idx3 = (((size_t)z * 16 + (c >> 6)) * 2048 + r) * 64 + (c & 63);
          ((bf16*)Cp)[idx3] = (bf16)v;
        } else if (CMODE == 4 || CMODE == 5) {
          atomicAdd(&((float*)Cp)[idx], v);
        } else if (CMODE == 6) {
          if ((z >> 1) == 0) {
            ((bf16*)Cp)[idx] = (bf16)v;
          } else {
            size_t idx3 = (((size_t)(z & 1) * 16 + (c >> 6)) * 2048 + r) * 64 + (c & 63);
            ((bf16*)resid)[idx3] = (bf16)(v * scale);
          }
        } else {
          if (CMODE == 2) v += resid[idx];
          ((float*)Cp)[idx] = v;
        }
      }
}

// ----------------------------------------------------------- flash attention
// attn7 (frozen): grid 512; light/heavy supertile split across grid; 8-wave
// blocks, kv halves, in-block flash-decode merge, exp2 softmax, defer-max.
static __device__ __forceinline__ unsigned pk2f(float a, float b) {
  union { bf16 h[2]; unsigned u; } x;
  x.h[0] = (bf16)a; x.h[1] = (bf16)b; return x.u;
}

__global__ __launch_bounds__(512, 2) void attn7_kernel(
    const bf16* __restrict__ Qg, const bf16* __restrict__ Khg,
    const bf16* __restrict__ Vtg, bf16* __restrict__ aog)
{
  __shared__ alignas(16) bf16 KS[2][2][4096];   // [half][dbuf][64x64]
  __shared__ alignas(16) bf16 VS[2][2][4096];
  const int lin = blockIdx.x;
  const int hb = lin & 31, jj = (lin >> 5) & 7, phase = lin >> 8;
  const int h = hb >> 1, b = hb & 1;
  const int t = threadIdx.x, w = t >> 6, l = t & 63;
  const int half = w >> 2, wsub = w & 3;
  const int qi = l & 31, hi = l >> 5;
  const bf16* Qb = Qg  + ((size_t)b * 2048) * 1024 + h * 64;
  const bf16* Kh = Khg + ((size_t)(b * 16 + h)) * 2048 * 64;
  const bf16* Vh = Vtg + ((size_t)b * 1024 + h * 64) * 2048;
  bf16* Ob = aog + ((size_t)b * 2048) * 1024 + h * 64;

  float* PO = (float*)&KS[0][0][0];             // merge area: [wsub*32+qi][65]
  float* MM = (float*)((char*)&KS[0][0][0] + 40960);
  float* LL = MM + 128;

  auto ISSUE = [&](int bi, int kv0) {
    bf16* ksb = &KS[half][bi][0];
    bf16* vsb = &VS[half][bi][0];
    #pragma unroll
    for (int i = 0; i < 2; ++i) {
      int c = wsub * 128 + i * 64 + l;
      int row = c >> 3;
      int scol = (c & 7) ^ (row & 7);
      gload_lds16(Kh + (size_t)(kv0 + row) * 64 + scol * 8,
                  (bf16*)((char*)ksb + wsub * 2048 + i * 1024));
    }
    #pragma unroll
    for (int i = 0; i < 2; ++i) {
      int c = wsub * 128 + i * 64 + l;
      int row = c >> 3;
      int scol = (c & 7) ^ (row & 7);
      gload_lds16(Vh + (size_t)row * 2048 + kv0 + scol * 8,
                  (bf16*)((char*)vsb + wsub * 2048 + i * 1024));
    }
  };

  const int T = phase ? (15 - jj) : jj;
  const int q0 = T * 128 + wsub * 32;
  const int base_g = half * (T + 1);

  bf16x8 qf[4];
  #pragma unroll
  for (int dc = 0; dc < 4; ++dc)
    qf[dc] = *(const bf16x8*)(Qb + (size_t)(q0 + qi) * 1024 + dc * 16 + hi * 8);

  f32x16 o0, o1;
  #pragma unroll
  for (int r = 0; r < 16; ++r) { o0[r] = 0.f; o1[r] = 0.f; }
  float m_run = -INFINITY, l_run = 0.f;

  ISSUE(0, base_g * 64);

  auto STEP64 = [&](int bi, int s0) {
    const bool h2 = (s0 + 32 <= q0);
    bf16x8 kf[8];
    const bf16* ksb = &KS[half][bi][0];
    const bf16* vsb = &VS[half][bi][0];
    const int kr1 = qi, kr2 = 32 + qi;
    #pragma unroll
    for (int dc = 0; dc < 4; ++dc) {
      kf[dc]     = *(const bf16x8*)((const char*)ksb + kr1 * 128 +
                                    (((dc * 2 + hi) ^ (kr1 & 7)) << 4));
      kf[4 + dc] = *(const bf16x8*)((const char*)ksb + kr2 * 128 +
                                    (((dc * 2 + hi) ^ (kr2 & 7)) << 4));
    }
    f32x16 sv1, sv2;
    #pragma unroll
    for (int r = 0; r < 16; ++r) { sv1[r] = 0.f; sv2[r] = 0.f; }
    __builtin_amdgcn_s_setprio(1);
    #pragma unroll
    for (int dc = 0; dc < 4; ++dc)
      sv1 = __builtin_amdgcn_mfma_f32_32x32x16_bf16(kf[dc], qf[dc], sv1, 0, 0, 0);
    if (h2) {
      #pragma unroll
      for (int dc = 0; dc < 4; ++dc)
        sv2 = __builtin_amdgcn_mfma_f32_32x32x16_bf16(kf[4 + dc], qf[dc], sv2, 0, 0, 0);
    }
    __builtin_amdgcn_s_setprio(0);
    const int qe = qi - 4 * hi;
    if (s0 == q0) {
      #pragma unroll
      for (int r = 0; r < 16; ++r) {
        const int kvc = (r & 3) + 8 * (r >> 2);
        sv1[r] = (kvc > qe) ? -INFINITY : sv1[r];
      }
    }
    if (h2 && s0 + 32 == q0) {
      #pragma unroll
      for (int r = 0; r < 16; ++r) {
        const int kvc = (r & 3) + 8 * (r >> 2);
        sv2[r] = (kvc > qe) ? -INFINITY : sv2[r];
      }
    }
    float mx[8];
    #pragma unroll
    for (int i = 0; i < 8; ++i) mx[i] = fmaxf(sv1[2 * i], sv1[2 * i + 1]);
    if (h2) {
      #pragma unroll
      for (int i = 0; i < 8; ++i) mx[i] = fmaxf(mx[i], fmaxf(sv2[2 * i], sv2[2 * i + 1]));
    }
    #pragma unroll
    for (int i = 0; i < 4; ++i) mx[i] = fmaxf(mx[i], mx[i + 4]);
    float tm = fmaxf(fmaxf(mx[0], mx[1]), fmaxf(mx[2], mx[3]));
    tm = fmaxf(tm, __shfl_xor(tm, 32));
    if (!__all(tm <= m_run + 11.0f)) {        // defer-max, THR=11 (exp2 dom)
      const float mn = fmaxf(m_run, tm);
      const float alpha = EXP2N(m_run - mn);
      m_run = mn;
      l_run *= alpha;
      o0 *= alpha; o1 *= alpha;
    }
    float rs = 0.f;
    unsigned pk[16], ot[16];
    #pragma unroll
    for (int i = 0; i < 8; ++i) {
      float pa = EXP2N(sv1[2 * i]     - m_run);
      float pb = EXP2N(sv1[2 * i + 1] - m_run);
      rs += pa + pb;
      pk[i] = pk2f(pa, pb);
    }
    if (h2) {
      #pragma unroll
      for (int i = 0; i < 8; ++i) {
        float pa = EXP2N(sv2[2 * i]     - m_run);
        float pb = EXP2N(sv2[2 * i + 1] - m_run);
        rs += pa + pb;
        pk[8 + i] = pk2f(pa, pb);
      }
    }
    rs += __shfl_xor(rs, 32);
    l_run += rs;
    #pragma unroll
    for (int i = 0; i < 8; ++i) ot[i] = __shfl_xor(pk[i], 32);
    if (h2) {
      #pragma unroll
      for (int i = 0; i < 8; ++i) ot[8 + i] = __shfl_xor(pk[8 + i], 32);
    }
    __builtin_amdgcn_s_setprio(1);
    #pragma unroll
    for (int c2 = 0; c2 < 4; ++c2) {
      if (c2 < 2 || h2) {
        union { unsigned u[4]; bf16x8 v; } pf;
        pf.u[0] = hi ? ot[4 * c2 + 2] : pk[4 * c2 + 0];
        pf.u[1] = hi ? ot[4 * c2 + 3] : pk[4 * c2 + 1];
        pf.u[2] = hi ? pk[4 * c2 + 2] : ot[4 * c2 + 0];
        pf.u[3] = hi ? pk[4 * c2 + 3] : ot[4 * c2 + 1];
        const int d0 = qi, d1 = 32 + qi;
        bf16x8 v0 = *(const bf16x8*)((const char*)vsb + d0 * 128 +
                                     (((c2 * 2 + hi) ^ (d0 & 7)) << 4));
        bf16x8 v1 = *(const bf16x8*)((const char*)vsb + d1 * 128 +
                                     (((c2 * 2 + hi) ^ (d1 & 7)) << 4));
        o0 = __builtin_amdgcn_mfma_f32_32x32x16_bf16(v0, pf.v, o0, 0, 0, 0);
        o1 = __builtin_amdgcn_mfma_f32_32x32x16_bf16(v1, pf.v, o1, 0, 0, 0);
      }
    }
    __builtin_amdgcn_s_setprio(0);
  };

  #pragma unroll 1
  for (int st = 0; st <= T; ++st) {
    const int bi = st & 1;
    if (st < T) {
      ISSUE(bi ^ 1, (base_g + st + 1) * 64);
      asm volatile("s_waitcnt vmcnt(4)" ::: "memory");
    } else {
      asm volatile("s_waitcnt vmcnt(0)" ::: "memory");
    }
    __builtin_amdgcn_s_barrier();
    const int s0 = (base_g + st) * 64;
    if (s0 <= q0) STEP64(bi, s0);
    __builtin_amdgcn_s_barrier();
  }

  // ---- in-block flash-decode merge of the two kv-halves ----
  if (half == 1) {
    #pragma unroll
    for (int r = 0; r < 16; ++r) {
      const int d0 = (r & 3) + 8 * (r >> 2) + 4 * hi;
      PO[(wsub * 32 + qi) * 65 + d0]      = o0[r];
      PO[(wsub * 32 + qi) * 65 + 32 + d0] = o1[r];
    }
    if (hi == 0) { MM[wsub * 32 + qi] = m_run; LL[wsub * 32 + qi] = l_run; }
  }
  __syncthreads();
  if (half == 0) {
    const float m1 = MM[wsub * 32 + qi], l1 = LL[wsub * 32 + qi];
    const float m = fmaxf(m_run, m1);
    const float a0 = EXP2N(m_run - m), a1 = EXP2N(m1 - m);
    const float inv = 1.0f / (a0 * l_run + a1 * l1);
    #pragma unroll
    for (int rg = 0; rg < 4; ++rg) {
      union { bf16 h4[4]; unsigned long long u; } pr0, pr1;
      #pragma unroll
      for (int e = 0; e < 4; ++e) {
        const int r = rg * 4 + e;
        const int d0 = (r & 3) + 8 * (r >> 2) + 4 * hi;
        pr0.h4[e] = (bf16)((a0 * o0[r] + a1 * PO[(wsub * 32 + qi) * 65 + d0])      * inv);
        pr1.h4[e] = (bf16)((a0 * o1[r] + a1 * PO[(wsub * 32 + qi) * 65 + 32 + d0]) * inv);
      }
      *(unsigned long long*)(Ob + (size_t)(q0 + qi) * 1024 +  0 + rg * 8 + hi * 4) = pr0.u;
      *(unsigned long long*)(Ob + (size_t)(q0 + qi) * 1024 + 32 + rg * 8 + hi * 4) = pr1.u;
    }
  }
}

// ------------------------------------------------------------------ top-k v3
static __device__ __forceinline__ void ce_desc(float& a, float& b) {
  float hi = fmaxf(a, b), lo = fminf(a, b); a = hi; b = lo;
}
static __device__ __forceinline__ void merge8(float r[8], const float o[8]) {
  float c[8];
  #pragma unroll
  for (int i = 0; i < 8; ++i) c[i] = fmaxf(r[i], o[7 - i]);
  ce_desc(c[0], c[4]); ce_desc(c[1], c[5]); ce_desc(c[2], c[6]); ce_desc(c[3], c[7]);
  ce_desc(c[0], c[2]); ce_desc(c[1], c[3]); ce_desc(c[4], c[6]); ce_desc(c[5], c[7]);
  ce_desc(c[0], c[1]); ce_desc(c[2], c[3]); ce_desc(c[4], c[5]); ce_desc(c[6], c[7]);
  #pragma unroll
  for (int i = 0; i < 8; ++i) r[i] = c[i];
}
static __device__ __forceinline__ unsigned long long fkey(float v, int idx) {
  unsigned u = __float_as_uint(v);
  u = (u & 0x80000000u) ? ~u : (u | 0x80000000u);
  return ((unsigned long long)u << 32) | (unsigned)(0xFFFFFFFFu - (unsigned)idx);
}

__global__ __launch_bounds__(256) void topk3_kernel(
    const bf16* __restrict__ ms, const float* __restrict__ kV, float* __restrict__ outp)
{
  const int token = blockIdx.x;
  const int t = threadIdx.x, w = t >> 6, l = t & 63;
  __shared__ unsigned long long cand[4096];
  __shared__ float wmax[32];
  __shared__ float wv[8];
  __shared__ int   wi[8];
  __shared__ int   cnt;
  if (t == 0) cnt = 0;

  const bf16* mrow = ms + (size_t)token * 4096;
  float vv[16];
  #pragma unroll
  for (int c = 0; c < 2; ++c) {
    bf16x8 rv = ((const bf16x8*)mrow)[t + c * 256];
    #pragma unroll
    for (int j = 0; j < 8; ++j) vv[c * 8 + j] = (float)rv[j];
  }

  float m = vv[0];
  #pragma unroll
  for (int j = 1; j < 16; ++j) m = fmaxf(m, vv[j]);

  float r[8];
  r[0] = m;
  #pragma unroll
  for (int i = 1; i < 8; ++i) r[i] = -INFINITY;
  #pragma unroll
  for (int st = 0; st < 6; ++st) {
    const int off = 1 << st;
    float o[8];
    #pragma unroll
    for (int i = 0; i < 8; ++i) o[i] = __shfl_xor(r[i], off);
    merge8(r, o);
  }
  if (l == 0) {
    #pragma unroll
    for (int i = 0; i < 8; ++i) wmax[w * 8 + i] = r[i];
  }
  __syncthreads();

  float a[8], bb[8];
  #pragma unroll
  for (int i = 0; i < 8; ++i) { a[i] = wmax[i]; bb[i] = wmax[8 + i]; }
  merge8(a, bb);
  #pragma unroll
  for (int i = 0; i < 8; ++i) bb[i] = wmax[16 + i];
  {
    float c2[8];
    #pragma unroll
    for (int i = 0; i < 8; ++i) c2[i] = wmax[24 + i];
    merge8(bb, c2);
  }
  merge8(a, bb);
  const float t8 = a[7];

  #pragma unroll
  for (int c = 0; c < 2; ++c) {
    const int base = (t + c * 256) * 8;
    #pragma unroll
    for (int j = 0; j < 8; ++j) {
      float v = vv[c * 8 + j];
      if (v >= t8) { int pos = atomicAdd(&cnt, 1); cand[pos] = fkey(v, base + j); }
    }
  }
  __syncthreads();

  if (w == 0) {
    const int n = cnt;
    unsigned long long prev = ~0ULL;
    float vk[8]; int ik[8];
    #pragma unroll
    for (int k = 0; k < 8; ++k) {
      unsigned long long best = 0;
      for (int i = l; i < n; i += 64) {
        unsigned long long c = cand[i];
        if (c < prev && c > best) best = c;
      }
      #pragma unroll
      for (int st = 0; st < 6; ++st) {
        const int off = 1 << st;
        unsigned bh = (unsigned)(best >> 32), bl = (unsigned)best;
        unsigned oh = __shfl_xor(bh, off), ol = __shfl_xor(bl, off);
        unsigned long long ob = ((unsigned long long)oh << 32) | ol;
        if (ob > best) best = ob;
      }
      prev = best;
      unsigned u = (unsigned)(best >> 32);
      u = (u & 0x80000000u) ? (u ^ 0x80000000u) : ~u;
      vk[k] = __uint_as_float(u);
      ik[k] = (int)(0xFFFFFFFFu - (unsigned)(best & 0xFFFFFFFFu));
    }
    if (l == 0) {
      const float mx = vk[0];
      float den = 0.f, ex[8];
      #pragma unroll
      for (int k = 0; k < 8; ++k) { ex[k] = __expf(vk[k] - mx); den += ex[k]; }
      const float inv = 1.0f / den;
      #pragma unroll
      for (int k = 0; k < 8; ++k) { wv[k] = ex[k] * inv; wi[k] = ik[k]; }
    }
  }
  __syncthreads();

  float a0 = 0, a1 = 0, a2 = 0, a3 = 0;
  #pragma unroll
  for (int k = 0; k < 8; ++k) {
    const float wk = wv[k];
    float4 vr = *(const float4*)(kV + (size_t)wi[k] * 1024 + t * 4);
    a0 += wk * vr.x; a1 += wk * vr.y; a2 += wk * vr.z; a3 += wk * vr.w;
  }
  float4* op = (float4*)(outp + (size_t)token * 1024) + t;
  float4 cur = *op;
  cur.x += a0; cur.y += a1; cur.z += a2; cur.w += a3;
  *op = cur;
}

// ---------------------------------------------------------------- launcher
extern "C" void kernel_launch(void* const* d_in, const int* in_sizes, int n_in,
                              void* d_out, int out_size, void* d_ws, size_t ws_size,
                              hipStream_t stream)
{
  (void)in_sizes; (void)n_in; (void)out_size; (void)ws_size;
  const float* x    = (const float*)d_in[0];
  const float* imp  = (const float*)d_in[1];
  const float* Wc   = (const float*)d_in[2];
  const float* WQ   = (const float*)d_in[3];
  const float* WK   = (const float*)d_in[4];
  const float* WV   = (const float*)d_in[5];
  const float* Wm   = (const float*)d_in[6];
  const float* comp = (const float*)d_in[7];
  const float* expd = (const float*)d_in[8];
  const float* kK   = (const float*)d_in[9];
  const float* kV   = (const float*)d_in[10];
  const float* WO   = (const float*)d_in[11];
  const float* g1   = (const float*)d_in[12];
  const float* b1   = (const float*)d_in[13];
  const float* g2   = (const float*)d_in[14];
  const float* b2   = (const float*)d_in[15];
  float* out = (float*)d_out;
  char* ws = (char*)d_ws;
  const size_t MB = 1u << 20;
  // --- zeroed-scratch region (single memset): [ws, ws + 64KB + 12MB) ---
  float* racc    = (float*)(ws);                       // 20480 B
  float* logits1 = (float*)(ws + 64 * 1024);           // 2 MB
  float* logits2 = (float*)(ws + 64 * 1024 + 2 * MB);  // 2 MB
  float* accf1   = (float*)(ws + 64 * 1024 + 4 * MB);  // 4 MB
  float* accf2   = (float*)(ws + 64 * 1024 + 8 * MB);  // 4 MB
  bf16*  Wcatb   = (bf16*)(ws + 13 * MB);              // 256 KB (padded by cvt_all)
  char* ar = ws + 14 * MB;
  bf16* nx   = (bf16*)(ar);              // 8 MB
  bf16* sct  = (bf16*)(ar +  8 * MB);    // 1 MB  [b][R][D]
  bf16* eqt  = (bf16*)(ar +  9 * MB);    // 1 MB  [b][D][R]  (eqt/ekt/evt contiguous)
  bf16* evt  = (bf16*)(ar + 11 * MB);
  bf16* hb   = (bf16*)(ar + 12 * MB);    // 2 MB  [b][S][R]
  bf16* Qb   = (bf16*)(ar + 14 * MB);    // 8 MB each
  bf16* Kb   = (bf16*)(ar + 22 * MB);    // head-major [b][h][s][64]
  bf16* Vtb  = (bf16*)(ar + 30 * MB);    // 8 MB  [b][D][S]  (V transposed)
  bf16* aob  = (bf16*)(ar + 38 * MB);    // 8 MB
  bf16* WOb  = (bf16*)(ar + 46 * MB);    // 2 MB
  bf16* nx2  = (bf16*)(ar);
  bf16* mct  = (bf16*)(ar +  8 * MB);
  bf16* Qmb  = (bf16*)(ar +  9 * MB);    // 2 MB (dead eqt/ekt)
  bf16* kKb  = (bf16*)(ar + 11 * MB);    // 2 MB (dead evt/hb head)
  bf16* msb  = (bf16*)(ar + 13 * MB);    // 32 MB bf16 scores (dead Qb/Kb/Vtb/aob)

  hipMemsetAsync(ws, 0, 12 * MB + 65536, stream);
  cvt_all_kernel<<<2176, 256, 0, stream>>>(Wc, WQ, WK, WV, Wm, Wcatb, WO, WOb, kK, kKb);

  ln_kernel<<<4096, 256, 0, stream>>>(x, g1, b1, nx);
  gemm_bt<4><<<dim3(1, 32, 4), 512, 0, stream>>>(nx, Wcatb, logits1, nullptr,
        4096, 128, 256, 1024, 1024, 256L, 256L, 0L, 1.0f);
  route_pool_kernel<<<1024, 256, 0, stream>>>(logits1, imp, racc, 4, 0);
  mixA_kernel<<<dim3(64, 2, 2), 256, 0, stream>>>(comp, expd, racc, sct, eqt);
  // h = nx @ sct^T via split-K x2 (f32 atomic accum)
  gemm_bt<5><<<dim3(2, 16, 4), 512, 0, stream>>>(nx, sct, accf1, nullptr, 2048, 256, 512,
        1024, 1024, (long)2048 * 1024, (long)256 * 1024, (long)2048 * 256, 1.0f);
  cvt_bf16_kernel<<<1024, 256, 0, stream>>>(accf1, hb, 262144);
  // Q + K expand in one dispatch (CMODE 6); K head-major, prescale log2e/8
  gemm_bt<6><<<dim3(8, 16, 4), 512, 0, stream>>>(hb, eqt, Qb, (const float*)Kb,
        2048, 1024, 256, 256, 256,
        (long)2048 * 256, (long)1024 * 256, (long)2048 * 1024, 0.18033688f);
  // V produced TRANSPOSED: Vt[b][d][s]
  gemm_bt<0><<<dim3(16, 8, 2), 512, 0, stream>>>(evt, hb, Vtb, nullptr, 1024, 2048, 256,
        256, 256, (long)1024 * 256, (long)2048 * 256, (long)1024 * 2048, 1.0f);
  attn7_kernel<<<512, 512, 0, stream>>>(Qb, Kb, Vtb, aob);
  gemm_bt<2><<<dim3(8, 32, 1), 512, 0, stream>>>(aob, WOb, out, x, 4096, 1024, 1024,
        1024, 1024, 0L, 0L, 0L, 1.0f);
  ln_kernel<<<4096, 256, 0, stream>>>(out, g2, b2, nx2);
  gemm_bt<4><<<dim3(1, 32, 4), 512, 0, stream>>>(nx2, Wcatb + 64 * 1024, logits2, nullptr,
        4096, 128, 256, 1024, 1024, 256L, 256L, 0L, 1.0f);
  route_pool_kernel<<<1024, 256, 0, stream>>>(logits2, imp, racc, 1, 4);
  mixB_kernel<<<dim3(64, 1, 2), 256, 0, stream>>>(comp, racc, mct);
  // Qm = nx2 @ mct^T via split-K x2
  gemm_bt<5><<<dim3(2, 16, 4), 512, 0, stream>>>(nx2, mct, accf2, nullptr, 2048, 256, 512,
        1024, 1024, (long)2048 * 1024, (long)256 * 1024, (long)2048 * 256, 1.0f);
  cvt_bf16_kernel<<<1024, 256, 0, stream>>>(accf2, Qmb, 262144);
  // ms scores in bf16
  gemm_bt<0><<<dim3(32, 16, 2), 512, 0, stream>>>(Qmb, kKb, msb, nullptr, 2048, 4096, 256,
        256, 256, (long)2048 * 256, 0L, (long)2048 * 4096, 0.0625f);
  topk3_kernel<<<4096, 256, 0, stream>>>(msb, kV, out);
}

// Round 20
// 242.182 us; speedup vs baseline: 1.0193x; 1.0193x over previous
//
#include <hip/hip_runtime.h>
#include <hip/hip_bf16.h>
#include <math.h>

typedef __bf16 bf16;
typedef __attribute__((ext_vector_type(8))) __bf16 bf16x8;
typedef __attribute__((ext_vector_type(4))) __bf16 bf16x4;
typedef __attribute__((ext_vector_type(4))) float f32x4;
typedef __attribute__((ext_vector_type(16))) float f32x16;

#define EXP2N __builtin_amdgcn_exp2f   // bare v_exp_f32 (1 VALU op)

static __device__ __forceinline__ void gload_lds16(const bf16* g, bf16* l) {
  __builtin_amdgcn_global_load_lds((const __attribute__((address_space(1))) void*)g,
                                   (__attribute__((address_space(3))) void*)l, 16, 0, 0);
}

// ---------------------------------------------------------------- LayerNorm
__global__ __launch_bounds__(256) void ln_kernel(
    const float* __restrict__ x, const float* __restrict__ gam, const float* __restrict__ bet,
    bf16* __restrict__ nxo)
{
  const int token = blockIdx.x;
  const int t = threadIdx.x, w = t >> 6, l = t & 63;
  __shared__ float red1[4], red2[4];
  float4 xv = ((const float4*)(x + (size_t)token * 1024))[t];
  float s  = xv.x + xv.y + xv.z + xv.w;
  float sq = xv.x*xv.x + xv.y*xv.y + xv.z*xv.z + xv.w*xv.w;
  #pragma unroll
  for (int off = 32; off > 0; off >>= 1) { s += __shfl_xor(s, off); sq += __shfl_xor(sq, off); }
  if (l == 0) { red1[w] = s; red2[w] = sq; }
  __syncthreads();
  s  = red1[0] + red1[1] + red1[2] + red1[3];
  sq = red2[0] + red2[1] + red2[2] + red2[3];
  const float mu  = s * (1.f / 1024.f);
  const float var = sq * (1.f / 1024.f) - mu * mu;
  const float rs  = rsqrtf(var + 1e-5f);
  float4 gv = ((const float4*)gam)[t];
  float4 bv = ((const float4*)bet)[t];
  bf16x4 pk = {(bf16)((xv.x - mu) * rs * gv.x + bv.x),
               (bf16)((xv.y - mu) * rs * gv.y + bv.y),
               (bf16)((xv.z - mu) * rs * gv.z + bv.z),
               (bf16)((xv.w - mu) * rs * gv.w + bv.w)};
  *(bf16x4*)(nxo + (size_t)token * 1024 + t * 4) = pk;
}

// --------------------------------------------------- route pool (from logits)
__global__ __launch_bounds__(256) void route_pool_kernel(
    const float* __restrict__ logits, const float* __restrict__ imp,
    float* __restrict__ racc, int ng, int gbase)
{
  const int w = threadIdx.x >> 6, l = threadIdx.x & 63;
  const int token = blockIdx.x * 4 + w;
  const int b = token >> 11;
  const int g = l >> 4, e = l & 15;
  if (g < ng) {
    float v = logits[(size_t)token * 128 + g * 16 + e];
    float mx = v;
    #pragma unroll
    for (int off = 1; off < 16; off <<= 1) mx = fmaxf(mx, __shfl_xor(mx, off));
    float ex = __expf(v - mx);
    float sm = ex;
    #pragma unroll
    for (int off = 1; off < 16; off <<= 1) sm += __shfl_xor(sm, off);
    atomicAdd(racc + ((((size_t)(token & 31)) * 5 + gbase + g) * 2 + b) * 16 + e,
              imp[token] * (ex / sm));
  }
}

// ----------------------------------- fused phase-A mixes (sct + eqt/ekt/evt)
__global__ __launch_bounds__(256) void mixA_kernel(
    const float* __restrict__ comp, const float* __restrict__ expd,
    const float* __restrict__ racc, bf16* __restrict__ sct, bf16* __restrict__ eqt)
{
  const int xb = blockIdx.x, sel = blockIdx.y, b = blockIdx.z;
  const int t = threadIdx.x;
  __shared__ float tile[64][65];
  __shared__ float psh[3][16];
  __shared__ float dsh[3];
  if (sel == 0) {
    if (t < 16) {
      float s = 0.f;
      for (int sl = 0; sl < 32; ++sl) s += racc[(((size_t)sl * 5 + 0) * 2 + b) * 16 + t];
      psh[0][t] = s;
    }
  } else {
    if (t < 48) {
      const int g = t >> 4, e = t & 15;
      float s = 0.f;
      for (int sl = 0; sl < 32; ++sl) s += racc[(((size_t)sl * 5 + 1 + g) * 2 + b) * 16 + e];
      psh[g][e] = s;
    }
  }
  __syncthreads();
  if (t < ((sel == 0) ? 1 : 3)) {
    float den = 1e-8f;
    #pragma unroll
    for (int e = 0; e < 16; ++e) den += psh[t][e];
    dsh[t] = 1.0f / den;
  }
  __syncthreads();

  const int ri = t >> 2, cc = (t & 3) << 4;
  if (sel == 0) {
    const int i0 = (xb & 15) * 64, j0 = (xb >> 4) * 64;
    const float inv = dsh[0];
    float acc[16];
    #pragma unroll
    for (int k = 0; k < 16; ++k) acc[k] = 0.f;
    const float* src0 = comp + ((size_t)(i0 + ri)) * 256 + j0 + cc;
    #pragma unroll 4
    for (int n = 0; n < 16; ++n) {
      const float wv = psh[0][n] * inv;
      const float4* sp = (const float4*)(src0 + (size_t)n * 262144);
      #pragma unroll
      for (int q = 0; q < 4; ++q) {
        float4 v = sp[q];
        acc[q*4+0] += wv * v.x; acc[q*4+1] += wv * v.y;
        acc[q*4+2] += wv * v.z; acc[q*4+3] += wv * v.w;
      }
    }
    #pragma unroll
    for (int k = 0; k < 16; ++k) tile[ri][cc + k] = acc[k];
    __syncthreads();
    union { bf16 h[16]; bf16x8 v[2]; } ob;
    #pragma unroll
    for (int k = 0; k < 16; ++k) ob.h[k] = (bf16)tile[cc + k][ri];
    bf16* dst = sct + ((size_t)b * 256 + j0 + ri) * 1024 + i0 + cc;
    ((bf16x8*)dst)[0] = ob.v[0];
    ((bf16x8*)dst)[1] = ob.v[1];
  } else {
    const int i0 = (xb & 3) * 64, j0 = (xb >> 2) * 64;
    const float inv0 = dsh[0], inv1 = dsh[1], inv2 = dsh[2];
    float acc[3][16];
    #pragma unroll
    for (int g = 0; g < 3; ++g)
      #pragma unroll
      for (int k = 0; k < 16; ++k) acc[g][k] = 0.f;
    const float* src0 = expd + ((size_t)(i0 + ri)) * 1024 + j0 + cc;
    #pragma unroll 2
    for (int n = 0; n < 16; ++n) {
      const float w0 = psh[0][n] * inv0;
      const float w1 = psh[1][n] * inv1;
      const float w2 = psh[2][n] * inv2;
      const float4* sp = (const float4*)(src0 + (size_t)n * 262144);
      #pragma unroll
      for (int q = 0; q < 4; ++q) {
        float4 v = sp[q];
        acc[0][q*4+0] += w0 * v.x; acc[0][q*4+1] += w0 * v.y;
        acc[0][q*4+2] += w0 * v.z; acc[0][q*4+3] += w0 * v.w;
        acc[1][q*4+0] += w1 * v.x; acc[1][q*4+1] += w1 * v.y;
        acc[1][q*4+2] += w1 * v.z; acc[1][q*4+3] += w1 * v.w;
        acc[2][q*4+0] += w2 * v.x; acc[2][q*4+1] += w2 * v.y;
        acc[2][q*4+2] += w2 * v.z; acc[2][q*4+3] += w2 * v.w;
      }
    }
    #pragma unroll 1
    for (int g = 0; g < 3; ++g) {
      __syncthreads();
      #pragma unroll
      for (int k = 0; k < 16; ++k) tile[ri][cc + k] = acc[g][k];
      __syncthreads();
      union { bf16 h[16]; bf16x8 v[2]; } ob;
      #pragma unroll
      for (int k = 0; k < 16; ++k) ob.h[k] = (bf16)tile[cc + k][ri];
      bf16* dst = eqt + (size_t)g * 524288 + ((size_t)b * 1024 + j0 + ri) * 256 + i0 + cc;
      ((bf16x8*)dst)[0] = ob.v[0];
      ((bf16x8*)dst)[1] = ob.v[1];
    }
  }
}

// ------------------------------------- phase-B mix (mct, group 4, inline rw)
__global__ __launch_bounds__(256) void mixB_kernel(
    const float* __restrict__ comp, const float* __restrict__ racc,
    bf16* __restrict__ out)
{
  const int xb = blockIdx.x, b = blockIdx.z;
  const int t = threadIdx.x;
  __shared__ float tile[64][65];
  __shared__ float psh[16];
  __shared__ float dsh1;
  if (t < 16) {
    float s = 0.f;
    for (int sl = 0; sl < 32; ++sl) s += racc[(((size_t)sl * 5 + 4) * 2 + b) * 16 + t];
    psh[t] = s;
  }
  __syncthreads();
  if (t == 0) {
    float den = 1e-8f;
    #pragma unroll
    for (int e = 0; e < 16; ++e) den += psh[e];
    dsh1 = 1.0f / den;
  }
  __syncthreads();
  const int ri = t >> 2, cc = (t & 3) << 4;
  const int i0 = (xb & 15) * 64, j0 = (xb >> 4) * 64;
  const float inv = dsh1;
  float acc[16];
  #pragma unroll
  for (int k = 0; k < 16; ++k) acc[k] = 0.f;
  const float* src0 = comp + ((size_t)(i0 + ri)) * 256 + j0 + cc;
  #pragma unroll 4
  for (int n = 0; n < 16; ++n) {
    const float wv = psh[n] * inv;
    const float4* sp = (const float4*)(src0 + (size_t)n * 262144);
    #pragma unroll
    for (int q = 0; q < 4; ++q) {
      float4 v = sp[q];
      acc[q*4+0] += wv * v.x; acc[q*4+1] += wv * v.y;
      acc[q*4+2] += wv * v.z; acc[q*4+3] += wv * v.w;
    }
  }
  #pragma unroll
  for (int k = 0; k < 16; ++k) tile[ri][cc + k] = acc[k];
  __syncthreads();
  union { bf16 h[16]; bf16x8 v[2]; } ob;
  #pragma unroll
  for (int k = 0; k < 16; ++k) ob.h[k] = (bf16)tile[cc + k][ri];
  bf16* dst = out + ((size_t)b * 256 + j0 + ri) * 1024 + i0 + cc;
  ((bf16x8*)dst)[0] = ob.v[0];
  ((bf16x8*)dst)[1] = ob.v[1];
}

// ------------------------------------------------------------ f32 -> bf16
__global__ void cvt_bf16_kernel(const float* __restrict__ in, bf16* __restrict__ out, int n4)
{
  const int i = blockIdx.x * 256 + threadIdx.x;
  if (i < n4) {
    float4 v = ((const float4*)in)[i];
    bf16x4 o = {(bf16)v.x, (bf16)v.y, (bf16)v.z, (bf16)v.w};
    ((bf16x4*)out)[i] = o;
  }
}

// -------------------- all weight conversions: Wcat(pad) + WO + kK in one
__global__ void cvt_all_kernel(
    const float* __restrict__ w0, const float* __restrict__ w1,
    const float* __restrict__ w2, const float* __restrict__ w3,
    const float* __restrict__ w4, bf16* __restrict__ wcat,
    const float* __restrict__ wo, bf16* __restrict__ woo,
    const float* __restrict__ kk, bf16* __restrict__ kko)
{
  int i = blockIdx.x * 256 + threadIdx.x;
  if (i < 32768) {
    const int seg = i >> 12;
    bf16x4 o;
    if (seg < 5) {
      const float* src = (seg == 0) ? w0 : (seg == 1) ? w1 : (seg == 2) ? w2
                       : (seg == 3) ? w3 : w4;
      float4 v = ((const float4*)src)[i & 4095];
      o = (bf16x4){(bf16)v.x, (bf16)v.y, (bf16)v.z, (bf16)v.w};
    } else {
      o = (bf16x4){(bf16)0.f, (bf16)0.f, (bf16)0.f, (bf16)0.f};
    }
    ((bf16x4*)wcat)[i] = o;
  } else {
    i -= 32768;
    if (i < 262144) {
      float4 v = ((const float4*)wo)[i];
      ((bf16x4*)woo)[i] = (bf16x4){(bf16)v.x, (bf16)v.y, (bf16)v.z, (bf16)v.w};
    } else {
      i -= 262144;
      float4 v = ((const float4*)kk)[i];
      ((bf16x4*)kko)[i] = (bf16x4){(bf16)v.x, (bf16)v.y, (bf16)v.z, (bf16)v.w};
    }
  }
}

// --------------------------------------------------------------- GEMM (Bt)
// 8-wave blocks, global_load_lds staging, 2-buffer 1-barrier loop (round-18
// best-measured). BM64 template variant: 64-row M-tile (acc[2][2]/wave,
// A-tile 4KB staged by threads<256) -- doubles grid of the low-occupancy
// GEMMs (WO/V/h/logits were at <=1 block/CU) to 2 blocks/CU, 4 waves/SIMD.
// CMODE: 0 = bf16 out, 1 = f32 out, 2 = f32 out + f32 resid,
//        3 = bf16 out head-major, 4/5 = f32 atomicAdd split-K variants,
//        6 = dual bf16 out (Q normal + K head-major*scale).
template<int CMODE, int BM64>
__global__ __launch_bounds__(512) void gemm_bt(
    const bf16* __restrict__ A, const bf16* __restrict__ Bt, void* __restrict__ Cp,
    const float* __restrict__ resid, int M, int N, int K, int lda, int ldb,
    long sA, long sB, long sC, float scale)
{
  constexpr int ASZ = BM64 ? 2048 : 4096;
  constexpr int FI  = BM64 ? 2 : 4;
  constexpr int WMS = BM64 ? 32 : 64;
  __shared__ alignas(16) bf16 As[2][ASZ];
  __shared__ alignas(16) bf16 Bs[2][4096];
  const int t = threadIdx.x, w = t >> 6, l = t & 63;
  const int llo = l & 15, lhi = l >> 4;
  const int wm = w >> 2, wn = w & 3;
  const int m0 = blockIdx.y * (BM64 ? 64 : 128), n0 = blockIdx.x * 128;
  const int z = blockIdx.z;
  const bf16* Ab;
  const bf16* Bb;
  if (CMODE == 5) {
    Ab = A  + (size_t)(z >> 1) * sA + (size_t)(z & 1) * K;
    Bb = Bt + (size_t)(z >> 1) * sB + (size_t)(z & 1) * K;
  } else if (CMODE == 6) {
    Ab = A  + (size_t)(z & 1) * sA;
    Bb = Bt + (size_t)(z >> 1) * 524288 + (size_t)(z & 1) * sB;
  } else {
    Ab = A  + (size_t)z * sA;
    Bb = Bt + (size_t)z * sB;
  }
  f32x4 acc[FI][2];
  #pragma unroll
  for (int i = 0; i < FI; ++i)
    #pragma unroll
    for (int j = 0; j < 2; ++j) acc[i][j] = (f32x4){0.f, 0.f, 0.f, 0.f};

  const int arow = t >> 2, akb = t & 3;
  const int akbs = akb ^ ((arow >> 1) & 3);      // pre-swizzled source column
  const bf16* asrc = Ab + (size_t)(m0 + arow) * lda + akbs * 8;
  const bf16* bsrc = Bb + (size_t)(n0 + arow) * ldb + akbs * 8;
  const bool doA = BM64 ? (t < 256) : true;
  bf16* adst0 = &As[0][(BM64 ? (t & 255) : t) * 8];
  bf16* adst1 = &As[1][(BM64 ? (t & 255) : t) * 8];
  bf16* bdst0 = &Bs[0][t * 8];
  bf16* bdst1 = &Bs[1][t * 8];

  if (doA) gload_lds16(asrc, adst0);
  gload_lds16(bsrc, bdst0);

  int buf = 0;
  for (int kt = 0; kt < K; kt += 32) {
    __syncthreads();                             // drains this buf's loads
    if (kt + 32 < K) {
      if (doA) gload_lds16(asrc + kt + 32, buf ? adst0 : adst1);
      gload_lds16(bsrc + kt + 32, buf ? bdst0 : bdst1);
    }
    const bf16* Asb = As[buf];
    const bf16* Bsb = Bs[buf];
    bf16x8 af[FI], bfr[2];
    #pragma unroll
    for (int fi = 0; fi < FI; ++fi) {
      int r = wm * WMS + fi * 16 + llo;
      af[fi] = *(const bf16x8*)((const char*)Asb + (r * 64 + ((lhi * 16) ^ (((r >> 1) & 3) << 4))));
    }
    #pragma unroll
    for (int fj = 0; fj < 2; ++fj) {
      int c = wn * 32 + fj * 16 + llo;
      bfr[fj] = *(const bf16x8*)((const char*)Bsb + (c * 64 + ((lhi * 16) ^ (((c >> 1) & 3) << 4))));
    }
    #pragma unroll
    for (int fi = 0; fi < FI; ++fi)
      #pragma unroll
      for (int fj = 0; fj < 2; ++fj)
        acc[fi][fj] = __builtin_amdgcn_mfma_f32_16x16x32_bf16(af[fi], bfr[fj], acc[fi][fj], 0, 0, 0);
    buf ^= 1;
  }

  size_t cbase;
  if (CMODE == 4) cbase = 0;
  else if (CMODE == 5) cbase = (size_t)(z >> 1) * sC;
  else if (CMODE == 6) cbase = (size_t)(z & 1) * sC;
  else cbase = (size_t)z * sC;

  #pragma unroll
  for (int fi = 0; fi < FI; ++fi)
    #pragma unroll
    for (int fj = 0; fj < 2; ++fj)
      #pragma unroll
      for (int jj = 0; jj < 4; ++jj) {
        int r = m0 + wm * WMS + fi * 16 + lhi * 4 + jj;
        int c = n0 + wn * 32 + fj * 16 + llo;
        size_t idx = cbase + (size_t)r * N + c;
        float v = acc[fi][fj][jj] * ((CMODE == 6) ? 1.0f : scale);
        if (CMODE == 0) {
          ((bf16*)Cp)[idx] = (bf16)v;
        } else if (CMODE == 3) {
          size_t idx3 = (((size_t)z * 16 + (c >> 6)) * 2048 + r) * 64 + (c & 63);
          ((bf16*)Cp)[idx3] = (bf16)v;
        } else if (CMODE == 4 || CMODE == 5) {
          atomicAdd(&((float*)Cp)[idx], v);
        } else if (CMODE == 6) {
          if ((z >> 1) == 0) {
            ((bf16*)Cp)[idx] = (bf16)v;
          } else {
            size_t idx3 = (((size_t)(z & 1) * 16 + (c >> 6)) * 2048 + r) * 64 + (c & 63);
            ((bf16*)resid)[idx3] = (bf16)(v * scale);
          }
        } else {
          if (CMODE == 2) v += resid[idx];
          ((float*)Cp)[idx] = v;
        }
      }
}

// ----------------------------------------------------------- flash attention
// attn7 (frozen): grid 512; light/heavy supertile split across grid; 8-wave
// blocks, kv halves, in-block flash-decode merge, exp2 softmax, defer-max.
static __device__ __forceinline__ unsigned pk2f(float a, float b) {
  union { bf16 h[2]; unsigned u; } x;
  x.h[0] = (bf16)a; x.h[1] = (bf16)b; return x.u;
}

__global__ __launch_bounds__(512, 2) void attn7_kernel(
    const bf16* __restrict__ Qg, const bf16* __restrict__ Khg,
    const bf16* __restrict__ Vtg, bf16* __restrict__ aog)
{
  __shared__ alignas(16) bf16 KS[2][2][4096];   // [half][dbuf][64x64]
  __shared__ alignas(16) bf16 VS[2][2][4096];
  const int lin = blockIdx.x;
  const int hb = lin & 31, jj = (lin >> 5) & 7, phase = lin >> 8;
  const int h = hb >> 1, b = hb & 1;
  const int t = threadIdx.x, w = t >> 6, l = t & 63;
  const int half = w >> 2, wsub = w & 3;
  const int qi = l & 31, hi = l >> 5;
  const bf16* Qb = Qg  + ((size_t)b * 2048) * 1024 + h * 64;
  const bf16* Kh = Khg + ((size_t)(b * 16 + h)) * 2048 * 64;
  const bf16* Vh = Vtg + ((size_t)b * 1024 + h * 64) * 2048;
  bf16* Ob = aog + ((size_t)b * 2048) * 1024 + h * 64;

  float* PO = (float*)&KS[0][0][0];             // merge area: [wsub*32+qi][65]
  float* MM = (float*)((char*)&KS[0][0][0] + 40960);
  float* LL = MM + 128;

  auto ISSUE = [&](int bi, int kv0) {
    bf16* ksb = &KS[half][bi][0];
    bf16* vsb = &VS[half][bi][0];
    #pragma unroll
    for (int i = 0; i < 2; ++i) {
      int c = wsub * 128 + i * 64 + l;
      int row = c >> 3;
      int scol = (c & 7) ^ (row & 7);
      gload_lds16(Kh + (size_t)(kv0 + row) * 64 + scol * 8,
                  (bf16*)((char*)ksb + wsub * 2048 + i * 1024));
    }
    #pragma unroll
    for (int i = 0; i < 2; ++i) {
      int c = wsub * 128 + i * 64 + l;
      int row = c >> 3;
      int scol = (c & 7) ^ (row & 7);
      gload_lds16(Vh + (size_t)row * 2048 + kv0 + scol * 8,
                  (bf16*)((char*)vsb + wsub * 2048 + i * 1024));
    }
  };

  const int T = phase ? (15 - jj) : jj;
  const int q0 = T * 128 + wsub * 32;
  const int base_g = half * (T + 1);

  bf16x8 qf[4];
  #pragma unroll
  for (int dc = 0; dc < 4; ++dc)
    qf[dc] = *(const bf16x8*)(Qb + (size_t)(q0 + qi) * 1024 + dc * 16 + hi * 8);

  f32x16 o0, o1;
  #pragma unroll
  for (int r = 0; r < 16; ++r) { o0[r] = 0.f; o1[r] = 0.f; }
  float m_run = -INFINITY, l_run = 0.f;

  ISSUE(0, base_g * 64);

  auto STEP64 = [&](int bi, int s0) {
    const bool h2 = (s0 + 32 <= q0);
    bf16x8 kf[8];
    const bf16* ksb = &KS[half][bi][0];
    const bf16* vsb = &VS[half][bi][0];
    const int kr1 = qi, kr2 = 32 + qi;
    #pragma unroll
    for (int dc = 0; dc < 4; ++dc) {
      kf[dc]     = *(const bf16x8*)((const char*)ksb + kr1 * 128 +
                                    (((dc * 2 + hi) ^ (kr1 & 7)) << 4));
      kf[4 + dc] = *(const bf16x8*)((const char*)ksb + kr2 * 128 +
                                    (((dc * 2 + hi) ^ (kr2 & 7)) << 4));
    }
    f32x16 sv1, sv2;
    #pragma unroll
    for (int r = 0; r < 16; ++r) { sv1[r] = 0.f; sv2[r] = 0.f; }
    __builtin_amdgcn_s_setprio(1);
    #pragma unroll
    for (int dc = 0; dc < 4; ++dc)
      sv1 = __builtin_amdgcn_mfma_f32_32x32x16_bf16(kf[dc], qf[dc], sv1, 0, 0, 0);
    if (h2) {
      #pragma unroll
      for (int dc = 0; dc < 4; ++dc)
        sv2 = __builtin_amdgcn_mfma_f32_32x32x16_bf16(kf[4 + dc], qf[dc], sv2, 0, 0, 0);
    }
    __builtin_amdgcn_s_setprio(0);
    const int qe = qi - 4 * hi;
    if (s0 == q0) {
      #pragma unroll
      for (int r = 0; r < 16; ++r) {
        const int kvc = (r & 3) + 8 * (r >> 2);
        sv1[r] = (kvc > qe) ? -INFINITY : sv1[r];
      }
    }
    if (h2 && s0 + 32 == q0) {
      #pragma unroll
      for (int r = 0; r < 16; ++r) {
        const int kvc = (r & 3) + 8 * (r >> 2);
        sv2[r] = (kvc > qe) ? -INFINITY : sv2[r];
      }
    }
    float mx[8];
    #pragma unroll
    for (int i = 0; i < 8; ++i) mx[i] = fmaxf(sv1[2 * i], sv1[2 * i + 1]);
    if (h2) {
      #pragma unroll
      for (int i = 0; i < 8; ++i) mx[i] = fmaxf(mx[i], fmaxf(sv2[2 * i], sv2[2 * i + 1]));
    }
    #pragma unroll
    for (int i = 0; i < 4; ++i) mx[i] = fmaxf(mx[i], mx[i + 4]);
    float tm = fmaxf(fmaxf(mx[0], mx[1]), fmaxf(mx[2], mx[3]));
    tm = fmaxf(tm, __shfl_xor(tm, 32));
    if (!__all(tm <= m_run + 11.0f)) {        // defer-max, THR=11 (exp2 dom)
      const float mn = fmaxf(m_run, tm);
      const float alpha = EXP2N(m_run - mn);
      m_run = mn;
      l_run *= alpha;
      o0 *= alpha; o1 *= alpha;
    }
    float rs = 0.f;
    unsigned pk[16], ot[16];
    #pragma unroll
    for (int i = 0; i < 8; ++i) {
      float pa = EXP2N(sv1[2 * i]     - m_run);
      float pb = EXP2N(sv1[2 * i + 1] - m_run);
      rs += pa + pb;
      pk[i] = pk2f(pa, pb);
    }
    if (h2) {
      #pragma unroll
      for (int i = 0; i < 8; ++i) {
        float pa = EXP2N(sv2[2 * i]     - m_run);
        float pb = EXP2N(sv2[2 * i + 1] - m_run);
        rs += pa + pb;
        pk[8 + i] = pk2f(pa, pb);
      }
    }
    rs += __shfl_xor(rs, 32);
    l_run += rs;
    #pragma unroll
    for (int i = 0; i < 8; ++i) ot[i] = __shfl_xor(pk[i], 32);
    if (h2) {
      #pragma unroll
      for (int i = 0; i < 8; ++i) ot[8 + i] = __shfl_xor(pk[8 + i], 32);
    }
    __builtin_amdgcn_s_setprio(1);
    #pragma unroll
    for (int c2 = 0; c2 < 4; ++c2) {
      if (c2 < 2 || h2) {
        union { unsigned u[4]; bf16x8 v; } pf;
        pf.u[0] = hi ? ot[4 * c2 + 2] : pk[4 * c2 + 0];
        pf.u[1] = hi ? ot[4 * c2 + 3] : pk[4 * c2 + 1];
        pf.u[2] = hi ? pk[4 * c2 + 2] : ot[4 * c2 + 0];
        pf.u[3] = hi ? pk[4 * c2 + 3] : ot[4 * c2 + 1];
        const int d0 = qi, d1 = 32 + qi;
        bf16x8 v0 = *(const bf16x8*)((const char*)vsb + d0 * 128 +
                                     (((c2 * 2 + hi) ^ (d0 & 7)) << 4));
        bf16x8 v1 = *(const bf16x8*)((const char*)vsb + d1 * 128 +
                                     (((c2 * 2 + hi) ^ (d1 & 7)) << 4));
        o0 = __builtin_amdgcn_mfma_f32_32x32x16_bf16(v0, pf.v, o0, 0, 0, 0);
        o1 = __builtin_amdgcn_mfma_f32_32x32x16_bf16(v1, pf.v, o1, 0, 0, 0);
      }
    }
    __builtin_amdgcn_s_setprio(0);
  };

  #pragma unroll 1
  for (int st = 0; st <= T; ++st) {
    const int bi = st & 1;
    if (st < T) {
      ISSUE(bi ^ 1, (base_g + st + 1) * 64);
      asm volatile("s_waitcnt vmcnt(4)" ::: "memory");
    } else {
      asm volatile("s_waitcnt vmcnt(0)" ::: "memory");
    }
    __builtin_amdgcn_s_barrier();
    const int s0 = (base_g + st) * 64;
    if (s0 <= q0) STEP64(bi, s0);
    __builtin_amdgcn_s_barrier();
  }

  // ---- in-block flash-decode merge of the two kv-halves ----
  if (half == 1) {
    #pragma unroll
    for (int r = 0; r < 16; ++r) {
      const int d0 = (r & 3) + 8 * (r >> 2) + 4 * hi;
      PO[(wsub * 32 + qi) * 65 + d0]      = o0[r];
      PO[(wsub * 32 + qi) * 65 + 32 + d0] = o1[r];
    }
    if (hi == 0) { MM[wsub * 32 + qi] = m_run; LL[wsub * 32 + qi] = l_run; }
  }
  __syncthreads();
  if (half == 0) {
    const float m1 = MM[wsub * 32 + qi], l1 = LL[wsub * 32 + qi];
    const float m = fmaxf(m_run, m1);
    const float a0 = EXP2N(m_run - m), a1 = EXP2N(m1 - m);
    const float inv = 1.0f / (a0 * l_run + a1 * l1);
    #pragma unroll
    for (int rg = 0; rg < 4; ++rg) {
      union { bf16 h4[4]; unsigned long long u; } pr0, pr1;
      #pragma unroll
      for (int e = 0; e < 4; ++e) {
        const int r = rg * 4 + e;
        const int d0 = (r & 3) + 8 * (r >> 2) + 4 * hi;
        pr0.h4[e] = (bf16)((a0 * o0[r] + a1 * PO[(wsub * 32 + qi) * 65 + d0])      * inv);
        pr1.h4[e] = (bf16)((a0 * o1[r] + a1 * PO[(wsub * 32 + qi) * 65 + 32 + d0]) * inv);
      }
      *(unsigned long long*)(Ob + (size_t)(q0 + qi) * 1024 +  0 + rg * 8 + hi * 4) = pr0.u;
      *(unsigned long long*)(Ob + (size_t)(q0 + qi) * 1024 + 32 + rg * 8 + hi * 4) = pr1.u;
    }
  }
}

// ------------------------------------------------------------------ top-k v3
static __device__ __forceinline__ void ce_desc(float& a, float& b) {
  float hi = fmaxf(a, b), lo = fminf(a, b); a = hi; b = lo;
}
static __device__ __forceinline__ void merge8(float r[8], const float o[8]) {
  float c[8];
  #pragma unroll
  for (int i = 0; i < 8; ++i) c[i] = fmaxf(r[i], o[7 - i]);
  ce_desc(c[0], c[4]); ce_desc(c[1], c[5]); ce_desc(c[2], c[6]); ce_desc(c[3], c[7]);
  ce_desc(c[0], c[2]); ce_desc(c[1], c[3]); ce_desc(c[4], c[6]); ce_desc(c[5], c[7]);
  ce_desc(c[0], c[1]); ce_desc(c[2], c[3]); ce_desc(c[4], c[5]); ce_desc(c[6], c[7]);
  #pragma unroll
  for (int i = 0; i < 8; ++i) r[i] = c[i];
}
static __device__ __forceinline__ unsigned long long fkey(float v, int idx) {
  unsigned u = __float_as_uint(v);
  u = (u & 0x80000000u) ? ~u : (u | 0x80000000u);
  return ((unsigned long long)u << 32) | (unsigned)(0xFFFFFFFFu - (unsigned)idx);
}

__global__ __launch_bounds__(256) void topk3_kernel(
    const bf16* __restrict__ ms, const float* __restrict__ kV, float* __restrict__ outp)
{
  const int token = blockIdx.x;
  const int t = threadIdx.x, w = t >> 6, l = t & 63;
  __shared__ unsigned long long cand[4096];
  __shared__ float wmax[32];
  __shared__ float wv[8];
  __shared__ int   wi[8];
  __shared__ int   cnt;
  if (t == 0) cnt = 0;

  const bf16* mrow = ms + (size_t)token * 4096;
  float vv[16];
  #pragma unroll
  for (int c = 0; c < 2; ++c) {
    bf16x8 rv = ((const bf16x8*)mrow)[t + c * 256];
    #pragma unroll
    for (int j = 0; j < 8; ++j) vv[c * 8 + j] = (float)rv[j];
  }

  float m = vv[0];
  #pragma unroll
  for (int j = 1; j < 16; ++j) m = fmaxf(m, vv[j]);

  float r[8];
  r[0] = m;
  #pragma unroll
  for (int i = 1; i < 8; ++i) r[i] = -INFINITY;
  #pragma unroll
  for (int st = 0; st < 6; ++st) {
    const int off = 1 << st;
    float o[8];
    #pragma unroll
    for (int i = 0; i < 8; ++i) o[i] = __shfl_xor(r[i], off);
    merge8(r, o);
  }
  if (l == 0) {
    #pragma unroll
    for (int i = 0; i < 8; ++i) wmax[w * 8 + i] = r[i];
  }
  __syncthreads();

  float a[8], bb[8];
  #pragma unroll
  for (int i = 0; i < 8; ++i) { a[i] = wmax[i]; bb[i] = wmax[8 + i]; }
  merge8(a, bb);
  #pragma unroll
  for (int i = 0; i < 8; ++i) bb[i] = wmax[16 + i];
  {
    float c2[8];
    #pragma unroll
    for (int i = 0; i < 8; ++i) c2[i] = wmax[24 + i];
    merge8(bb, c2);
  }
  merge8(a, bb);
  const float t8 = a[7];

  #pragma unroll
  for (int c = 0; c < 2; ++c) {
    const int base = (t + c * 256) * 8;
    #pragma unroll
    for (int j = 0; j < 8; ++j) {
      float v = vv[c * 8 + j];
      if (v >= t8) { int pos = atomicAdd(&cnt, 1); cand[pos] = fkey(v, base + j); }
    }
  }
  __syncthreads();

  if (w == 0) {
    const int n = cnt;
    unsigned long long prev = ~0ULL;
    float vk[8]; int ik[8];
    #pragma unroll
    for (int k = 0; k < 8; ++k) {
      unsigned long long best = 0;
      for (int i = l; i < n; i += 64) {
        unsigned long long c = cand[i];
        if (c < prev && c > best) best = c;
      }
      #pragma unroll
      for (int st = 0; st < 6; ++st) {
        const int off = 1 << st;
        unsigned bh = (unsigned)(best >> 32), bl = (unsigned)best;
        unsigned oh = __shfl_xor(bh, off), ol = __shfl_xor(bl, off);
        unsigned long long ob = ((unsigned long long)oh << 32) | ol;
        if (ob > best) best = ob;
      }
      prev = best;
      unsigned u = (unsigned)(best >> 32);
      u = (u & 0x80000000u) ? (u ^ 0x80000000u) : ~u;
      vk[k] = __uint_as_float(u);
      ik[k] = (int)(0xFFFFFFFFu - (unsigned)(best & 0xFFFFFFFFu));
    }
    if (l == 0) {
      const float mx = vk[0];
      float den = 0.f, ex[8];
      #pragma unroll
      for (int k = 0; k < 8; ++k) { ex[k] = __expf(vk[k] - mx); den += ex[k]; }
      const float inv = 1.0f / den;
      #pragma unroll
      for (int k = 0; k < 8; ++k) { wv[k] = ex[k] * inv; wi[k] = ik[k]; }
    }
  }
  __syncthreads();

  float a0 = 0, a1 = 0, a2 = 0, a3 = 0;
  #pragma unroll
  for (int k = 0; k < 8; ++k) {
    const float wk = wv[k];
    float4 vr = *(const float4*)(kV + (size_t)wi[k] * 1024 + t * 4);
    a0 += wk * vr.x; a1 += wk * vr.y; a2 += wk * vr.z; a3 += wk * vr.w;
  }
  float4* op = (float4*)(outp + (size_t)token * 1024) + t;
  float4 cur = *op;
  cur.x += a0; cur.y += a1; cur.z += a2; cur.w += a3;
  *op = cur;
}

// ---------------------------------------------------------------- launcher
extern "C" void kernel_launch(void* const* d_in, const int* in_sizes, int n_in,
                              void* d_out, int out_size, void* d_ws, size_t ws_size,
                              hipStream_t stream)
{
  (void)in_sizes; (void)n_in; (void)out_size; (void)ws_size;
  const float* x    = (const float*)d_in[0];
  const float* imp  = (const float*)d_in[1];
  const float* Wc   = (const float*)d_in[2];
  const float* WQ   = (const float*)d_in[3];
  const float* WK   = (const float*)d_in[4];
  const float* WV   = (const float*)d_in[5];
  const float* Wm   = (const float*)d_in[6];
  const float* comp = (const float*)d_in[7];
  const float* expd = (const float*)d_in[8];
  const float* kK   = (const float*)d_in[9];
  const float* kV   = (const float*)d_in[10];
  const float* WO   = (const float*)d_in[11];
  const float* g1   = (const float*)d_in[12];
  const float* b1   = (const float*)d_in[13];
  const float* g2   = (const float*)d_in[14];
  const float* b2   = (const float*)d_in[15];
  float* out = (float*)d_out;
  char* ws = (char*)d_ws;
  const size_t MB = 1u << 20;
  // --- zeroed-scratch region (single memset): [ws, ws + 64KB + 12MB) ---
  float* racc    = (float*)(ws);                       // 20480 B
  float* logits1 = (float*)(ws + 64 * 1024);           // 2 MB
  float* logits2 = (float*)(ws + 64 * 1024 + 2 * MB);  // 2 MB
  float* accf1   = (float*)(ws + 64 * 1024 + 4 * MB);  // 4 MB
  float* accf2   = (float*)(ws + 64 * 1024 + 8 * MB);  // 4 MB
  bf16*  Wcatb   = (bf16*)(ws + 13 * MB);              // 256 KB (padded by cvt_all)
  char* ar = ws + 14 * MB;
  bf16* nx   = (bf16*)(ar);              // 8 MB
  bf16* sct  = (bf16*)(ar +  8 * MB);    // 1 MB  [b][R][D]
  bf16* eqt  = (bf16*)(ar +  9 * MB);    // 1 MB  [b][D][R]  (eqt/ekt/evt contiguous)
  bf16* evt  = (bf16*)(ar + 11 * MB);
  bf16* hb   = (bf16*)(ar + 12 * MB);    // 2 MB  [b][S][R]
  bf16* Qb   = (bf16*)(ar + 14 * MB);    // 8 MB each
  bf16* Kb   = (bf16*)(ar + 22 * MB);    // head-major [b][h][s][64]
  bf16* Vtb  = (bf16*)(ar + 30 * MB);    // 8 MB  [b][D][S]  (V transposed)
  bf16* aob  = (bf16*)(ar + 38 * MB);    // 8 MB
  bf16* WOb  = (bf16*)(ar + 46 * MB);    // 2 MB
  bf16* nx2  = (bf16*)(ar);
  bf16* mct  = (bf16*)(ar +  8 * MB);
  bf16* Qmb  = (bf16*)(ar +  9 * MB);    // 2 MB (dead eqt/ekt)
  bf16* kKb  = (bf16*)(ar + 11 * MB);    // 2 MB (dead evt/hb head)
  bf16* msb  = (bf16*)(ar + 13 * MB);    // 32 MB bf16 scores (dead Qb/Kb/Vtb/aob)

  hipMemsetAsync(ws, 0, 12 * MB + 65536, stream);
  cvt_all_kernel<<<2176, 256, 0, stream>>>(Wc, WQ, WK, WV, Wm, Wcatb, WO, WOb, kK, kKb);

  ln_kernel<<<4096, 256, 0, stream>>>(x, g1, b1, nx);
  gemm_bt<4, 1><<<dim3(1, 64, 4), 512, 0, stream>>>(nx, Wcatb, logits1, nullptr,
        4096, 128, 256, 1024, 1024, 256L, 256L, 0L, 1.0f);
  route_pool_kernel<<<1024, 256, 0, stream>>>(logits1, imp, racc, 4, 0);
  mixA_kernel<<<dim3(64, 2, 2), 256, 0, stream>>>(comp, expd, racc, sct, eqt);
  // h = nx @ sct^T via split-K x2 (f32 atomic accum)
  gemm_bt<5, 1><<<dim3(2, 32, 4), 512, 0, stream>>>(nx, sct, accf1, nullptr, 2048, 256, 512,
        1024, 1024, (long)2048 * 1024, (long)256 * 1024, (long)2048 * 256, 1.0f);
  cvt_bf16_kernel<<<1024, 256, 0, stream>>>(accf1, hb, 262144);
  // Q + K expand in one dispatch (CMODE 6); K head-major, prescale log2e/8
  gemm_bt<6, 0><<<dim3(8, 16, 4), 512, 0, stream>>>(hb, eqt, Qb, (const float*)Kb,
        2048, 1024, 256, 256, 256,
        (long)2048 * 256, (long)1024 * 256, (long)2048 * 1024, 0.18033688f);
  // V produced TRANSPOSED: Vt[b][d][s]
  gemm_bt<0, 1><<<dim3(16, 16, 2), 512, 0, stream>>>(evt, hb, Vtb, nullptr, 1024, 2048, 256,
        256, 256, (long)1024 * 256, (long)2048 * 256, (long)1024 * 2048, 1.0f);
  attn7_kernel<<<512, 512, 0, stream>>>(Qb, Kb, Vtb, aob);
  gemm_bt<2, 1><<<dim3(8, 64, 1), 512, 0, stream>>>(aob, WOb, out, x, 4096, 1024, 1024,
        1024, 1024, 0L, 0L, 0L, 1.0f);
  ln_kernel<<<4096, 256, 0, stream>>>(out, g2, b2, nx2);
  gemm_bt<4, 1><<<dim3(1, 64, 4), 512, 0, stream>>>(nx2, Wcatb + 64 * 1024, logits2, nullptr,
        4096, 128, 256, 1024, 1024, 256L, 256L, 0L, 1.0f);
  route_pool_kernel<<<1024, 256, 0, stream>>>(logits2, imp, racc, 1, 4);
  mixB_kernel<<<dim3(64, 1, 2), 256, 0, stream>>>(comp, racc, mct);
  // Qm = nx2 @ mct^T via split-K x2
  gemm_bt<5, 1><<<dim3(2, 32, 4), 512, 0, stream>>>(nx2, mct, accf2, nullptr, 2048, 256, 512,
        1024, 1024, (long)2048 * 1024, (long)256 * 1024, (long)2048 * 256, 1.0f);
  cvt_bf16_kernel<<<1024, 256, 0, stream>>>(accf2, Qmb, 262144);
  // ms scores in bf16
  gemm_bt<0, 0><<<dim3(32, 16, 2), 512, 0, stream>>>(Qmb, kKb, msb, nullptr, 2048, 4096, 256,
        256, 256, (long)2048 * 256, 0L, (long)2048 * 4096, 0.0625f);
  topk3_kernel<<<4096, 256, 0, stream>>>(msb, kV, out);
}